// Round 6
// baseline (32.142 us; speedup 1.0000x reference)
//
#include <hip/hip_runtime.h>
#include <hip/hip_bf16.h>
#include <math.h>

#define NB 8
#define NL 128
#define D_ATOM 256
#define DH 32       // d_hid
#define DAB 64      // 2*d_hid
#define K1 21
#define K2 30
#define KT 51       // K1+K2
#define ROWS (NB*NL) // 1024
#define LN_EPS 1e-5f

#define OUT1_ROW (NL*K1)      // 2688 floats
#define OUT2_ROW (NL*K2)      // 3840 floats
#define STAGE_N  (OUT1_ROW + OUT2_ROW) // 6528 floats

#define NTILES 104            // padded dk = d*52+k -> 1664/16
#define TROW_HW 2048          // per-row T fragments: 4 kt * 512 halfwords

typedef __attribute__((ext_vector_type(8))) short bf16x8;
typedef __attribute__((ext_vector_type(4))) float f32x4;

__device__ __forceinline__ unsigned short f2bf(float x) {
    __hip_bfloat16 h = __float2bfloat16(x);
    return *reinterpret_cast<unsigned short*>(&h);
}

// ---------------- Kernel 1: LN (blocks 0..255) + W-prep (blocks 256..268) ----
// LN: 4 rows/block; writes a/bb DIRECTLY as bf16 MFMA fragments.
//   a  -> af[mtile=row>>4][lane=(row&15)|((c>>3)<<4)][reg=c&7]      (A-frag)
//   bb -> bbf[batch][mtile=m>>4][lane=(m&15)|((d>>3)<<4)][reg=d&7]  (A-frag)
// W-prep: Wf[nt][lane=(dk&15)|((c>>3)<<4)][reg=c&7] = bf16(W[c,d,k]), dk=d*52+k,
//   pad k==51 -> 0. Coalesced u16 writes (widx linear in thread id).
__global__ __launch_bounds__(256) void ln_wprep_kernel(
    const float* __restrict__ z, const float* __restrict__ W_in,
    const float* __restrict__ b_in, const float* __restrict__ ln_g,
    const float* __restrict__ ln_b, const float* __restrict__ W1,
    const float* __restrict__ W2, unsigned short* __restrict__ af,
    unsigned short* __restrict__ bbf, unsigned short* __restrict__ Wf)
{
    const int t = threadIdx.x;

    if (blockIdx.x >= 256) {
        // ---- W-prep: 13 blocks * 256 threads * 16 els = 53248 = 104*512 ----
        const int base = ((int)blockIdx.x - 256) * 4096;
        #pragma unroll
        for (int e = 0; e < 16; ++e) {
            int widx = base + e * 256 + t;
            int nt = widx >> 9, lane = (widx >> 3) & 63, reg = widx & 7;
            int dk = nt * 16 + (lane & 15);
            int c  = ((lane >> 4) << 3) + reg;
            int d  = dk / 52, k = dk - d * 52;
            float v = 0.f;
            if (k < K1)      v = W1[(c * DH + d) * K1 + k];
            else if (k < KT) v = W2[(c * DH + d) * K2 + (k - K1)];
            Wf[widx] = f2bf(v);
        }
        return;
    }

    // ---- LN: 4 rows per block ----
    __shared__ float Wl[D_ATOM * DAB];   // 64 KB
    __shared__ float zl[4][D_ATOM];      // 4 KB
    const int w = t >> 6, j = t & 63;
    const int row0 = blockIdx.x * 4;

    #pragma unroll
    for (int s = 0; s < 16; ++s) {
        int i4 = t + s * 256;
        ((float4*)Wl)[i4] = ((const float4*)W_in)[i4];
    }
    ((float4*)zl)[t] = ((const float4*)(z + (size_t)row0 * D_ATOM))[t];
    __syncthreads();

    float acc = b_in[j];
    #pragma unroll 8
    for (int i = 0; i < D_ATOM; ++i)
        acc = fmaf(zl[w][i], Wl[i * DAB + j], acc);

    float g = 0.5f * acc * (1.0f + erff(acc * 0.70710678118654752f));

    float s = g, sq = g * g;
    #pragma unroll
    for (int msk = 1; msk < 64; msk <<= 1) {
        s  += __shfl_xor(s,  msk, 64);
        sq += __shfl_xor(sq, msk, 64);
    }
    float mu  = s  * (1.0f / 64.0f);
    float var = sq * (1.0f / 64.0f) - mu * mu;
    float y = (g - mu) * rsqrtf(var + LN_EPS) * ln_g[j] + ln_b[j];

    const int row = row0 + w;
    unsigned short hv = f2bf(y);
    if (j < DH) {
        const int c = j;
        af[((row >> 4) << 9) + ((((row & 15) | ((c >> 3) << 4)) << 3) | (c & 7))] = hv;
    } else {
        const int d = j - DH, m = row & 127, batch = row >> 7;
        bbf[batch * 4096 + ((m >> 4) << 9) +
            ((((m & 15) | ((d >> 3) << 4)) << 3) | (d & 7))] = hv;
    }
}

// ---------------- Kernel 2: T-GEMM (MFMA, W-stationary) ----------------
// Block = one row-mtile (16 rows). T[row][d][k] = sum_c a[row,c] * W[c,d,k].
// A = af mtile, B = Wf ntiles (N = dk, K = c). C scattered (u16) straight to
// T_ws in pair-B-fragment order: row*2048 + (k>>4)*512 + lane'*8 + reg',
// lane' = (k&15)|((d>>3)<<4), reg' = d&7. Pad cols (k==51) skipped.
__global__ __launch_bounds__(256) void t_gemm_kernel(
    const unsigned short* __restrict__ af, const unsigned short* __restrict__ Wf,
    unsigned short* __restrict__ T_ws)
{
    const int mt = blockIdx.x;           // 0..63
    const int w  = threadIdx.x >> 6, l = threadIdx.x & 63;

    const bf16x8 a = ((const bf16x8*)af)[mt * 64 + l];
    const int rowb = mt * 16 + ((l >> 4) << 2);

    for (int i = 0; i < 26; ++i) {
        const int nt = w * 26 + i;
        const bf16x8 b = ((const bf16x8*)Wf)[nt * 64 + l];
        f32x4 c = __builtin_amdgcn_mfma_f32_16x16x32_bf16(
            a, b, (f32x4){0.f, 0.f, 0.f, 0.f}, 0, 0, 0);
        const int dk = nt * 16 + (l & 15);
        const int d = dk / 52, k = dk - d * 52;
        if (k < KT) {
            const int off = ((k >> 4) << 9) +
                            ((((k & 15) | ((d >> 3) << 4)) << 3) | (d & 7));
            #pragma unroll
            for (int q = 0; q < 4; ++q)
                T_ws[(size_t)(rowb + q) * TROW_HW + off] = f2bf(c[q]);
        }
    }
}

// ---------------- Kernel 3: pair product (pure MFMA + copyout) ----------------
// 2 rows per block. Fragments loaded straight from ws into registers.
__global__ __launch_bounds__(256) void pair_kernel(
    const unsigned short* __restrict__ bbf, const unsigned short* __restrict__ T_ws,
    const float* __restrict__ b1v, const float* __restrict__ b2v,
    float* __restrict__ out)
{
    const int row0  = blockIdx.x * 2;
    const int batch = row0 >> 7;
    const int t     = threadIdx.x;
    const int w = t >> 6, l = t & 63;
    const int r = w >> 1;               // row within pair
    const int mh = w & 1;               // m-half

    __shared__ __align__(16) float stg[2][STAGE_N];   // 51 KB

    bf16x8 afr[4], bfr[4];
    #pragma unroll
    for (int i = 0; i < 4; ++i)
        afr[i] = ((const bf16x8*)bbf)[batch * 512 + (mh * 4 + i) * 64 + l];
    #pragma unroll
    for (int kt = 0; kt < 4; ++kt)
        bfr[kt] = ((const bf16x8*)T_ws)[(size_t)(row0 + r) * 256 + kt * 64 + l];

    float bias[4];
    #pragma unroll
    for (int kt = 0; kt < 4; ++kt) {
        int k = kt * 16 + (l & 15);
        bias[kt] = (k < K1) ? b1v[k] : (k < KT ? b2v[k - K1] : 0.f);
    }

    #pragma unroll
    for (int i = 0; i < 4; ++i) {
        const int mbase = (mh * 4 + i) * 16 + (l >> 4) * 4;
        #pragma unroll
        for (int kt = 0; kt < 4; ++kt) {
            f32x4 acc = __builtin_amdgcn_mfma_f32_16x16x32_bf16(
                afr[i], bfr[kt], (f32x4){0.f, 0.f, 0.f, 0.f}, 0, 0, 0);
            const int k = kt * 16 + (l & 15);
            if (k < K1) {
                #pragma unroll
                for (int q = 0; q < 4; ++q)
                    stg[r][(mbase + q) * K1 + k] = acc[q] + bias[kt];
            } else if (k < KT) {
                #pragma unroll
                for (int q = 0; q < 4; ++q)
                    stg[r][OUT1_ROW + (mbase + q) * K2 + (k - K1)] = acc[q] + bias[kt];
            }
        }
    }
    __syncthreads();

    #pragma unroll
    for (int rr = 0; rr < 2; ++rr) {
        const int row = row0 + rr;
        float* o1 = out + (size_t)row * OUT1_ROW;
        float* o2 = out + (size_t)ROWS * OUT1_ROW + (size_t)row * OUT2_ROW;
        const float4* s1 = (const float4*)stg[rr];
        const float4* s2 = (const float4*)(stg[rr] + OUT1_ROW);
        for (int i4 = t; i4 < OUT1_ROW / 4; i4 += 256)
            ((float4*)o1)[i4] = s1[i4];
        for (int i4 = t; i4 < OUT2_ROW / 4; i4 += 256)
            ((float4*)o2)[i4] = s2[i4];
    }
}

extern "C" void kernel_launch(void* const* d_in, const int* in_sizes, int n_in,
                              void* d_out, int out_size, void* d_ws, size_t ws_size,
                              hipStream_t stream) {
    const float* z    = (const float*)d_in[0];
    const float* W_in = (const float*)d_in[1];
    const float* b_in = (const float*)d_in[2];
    const float* ln_g = (const float*)d_in[3];
    const float* ln_b = (const float*)d_in[4];
    const float* W1   = (const float*)d_in[5];
    const float* b1   = (const float*)d_in[6];
    const float* W2   = (const float*)d_in[7];
    const float* b2   = (const float*)d_in[8];
    float* out = (float*)d_out;

    unsigned short* af   = (unsigned short*)d_ws;   // 32768 hw (64 KB)
    unsigned short* bbf  = af + 32768;              // 32768 hw (64 KB)
    unsigned short* Wf   = bbf + 32768;             // 53248 hw (104 KB)
    unsigned short* T_ws = Wf + 53248;              // 1024*2048 hw (4 MB)

    ln_wprep_kernel<<<269, 256, 0, stream>>>(z, W_in, b_in, ln_g, ln_b,
                                             W1, W2, af, bbf, Wf);
    t_gemm_kernel<<<64, 256, 0, stream>>>(af, Wf, T_ws);
    pair_kernel<<<ROWS / 2, 256, 0, stream>>>(bbf, T_ws, b1, b2, out);
}